// Round 1
// baseline (632.756 us; speedup 1.0000x reference)
//
#include <hip/hip_runtime.h>
#include <hip/hip_bf16.h>

typedef __attribute__((ext_vector_type(8))) short short8;
typedef __attribute__((ext_vector_type(4))) float f32x4;

#define NQ 95
#define HDIM 512
#define RBF 6
#define BM 64

static __device__ __forceinline__ unsigned short f2bf(float f){
  unsigned u = __float_as_uint(f);
  u += 0x7FFF + ((u >> 16) & 1);          // round-to-nearest-even
  return (unsigned short)(u >> 16);
}
static __device__ __forceinline__ float bf2f(unsigned short b){
  return __uint_as_float(((unsigned)b) << 16);
}
static __device__ __forceinline__ float swishf(float z){
  float e = __expf(-z);
  return z * __builtin_amdgcn_rcpf(1.0f + e);
}

// ---------------------------------------------------------------------------
// P0[v][n] = sum_k emb[v][k] * W_lin[k][n]        + b_lin[n]
// P1[v][n] = sum_k emb[v][k] * W_lin[512+k][n]
// grid: 190 blocks (95 rows x 2 tables), 256 threads
// ---------------------------------------------------------------------------
__global__ __launch_bounds__(256) void prep_tables(
    const float* __restrict__ emb, const float* __restrict__ W_lin,
    const float* __restrict__ b_lin, float* __restrict__ P0,
    float* __restrict__ P1)
{
  __shared__ float sE[HDIM];
  const int v   = blockIdx.x % NQ;
  const int tab = blockIdx.x / NQ;
  const int t   = threadIdx.x;
  sE[t]       = emb[v*HDIM + t];
  sE[t + 256] = emb[v*HDIM + t + 256];
  __syncthreads();
  const float* W = W_lin + (size_t)tab * HDIM * HDIM;
  float a0 = tab ? 0.f : b_lin[t];
  float a1 = tab ? 0.f : b_lin[t + 256];
  #pragma unroll 4
  for (int k = 0; k < HDIM; ++k){
    float ew = sE[k];
    a0 += ew * W[(size_t)k*HDIM + t];
    a1 += ew * W[(size_t)k*HDIM + t + 256];
  }
  float* P = tab ? P1 : P0;
  P[v*HDIM + t]       = a0;
  P[v*HDIM + t + 256] = a1;
}

// ---------------------------------------------------------------------------
// W2T[n][k] = bf16(W_lin[1024+k][n])   (512x512 bf16, row n-major)
// grid: 128 blocks x 256 threads, each thread writes 8 contiguous k (16B)
// ---------------------------------------------------------------------------
__global__ __launch_bounds__(256) void prep_w2t(
    const float* __restrict__ W_lin, unsigned short* __restrict__ W2T)
{
  const int idx = blockIdx.x * 256 + threadIdx.x;     // 0 .. 512*64
  const int n  = idx >> 6;
  const int kb = (idx & 63) * 8;
  const float* W2 = W_lin + (size_t)1024 * HDIM;
  unsigned p[4];
  #pragma unroll
  for (int c = 0; c < 4; ++c){
    unsigned lo = f2bf(W2[(size_t)(kb + 2*c    ) * HDIM + n]);
    unsigned hi = f2bf(W2[(size_t)(kb + 2*c + 1) * HDIM + n]);
    p[c] = lo | (hi << 16);
  }
  uint4 o; o.x = p[0]; o.y = p[1]; o.z = p[2]; o.w = p[3];
  *(uint4*)(W2T + (size_t)n * HDIM + kb) = o;
}

// ---------------------------------------------------------------------------
// Fused main kernel: per 64-edge block
//   A = swish(rbf@W0+b0) [64x512] bf16 in LDS (XOR-swizzled)
//   acc = A @ W2 via mfma_f32_16x16x32_bf16  (4 waves x 128 cols each)
//   g = rbf@W1 into same LDS
//   e1 = swish(acc + P0[x[i]] + P1[x[j]]);  e2 = g*e1
// ---------------------------------------------------------------------------
__global__ __launch_bounds__(256, 2) void fused_edge(
    const int* __restrict__ xv, const float* __restrict__ rbf,
    const int* __restrict__ ei, const int* __restrict__ ej,
    const float* __restrict__ W0, const float* __restrict__ b0,
    const float* __restrict__ W1,
    const float* __restrict__ P0, const float* __restrict__ P1,
    const unsigned short* __restrict__ W2T,
    float* __restrict__ out, int E)
{
  __shared__ unsigned short sA[BM * HDIM];   // 64 KB; rbf0-tile then g-tile
  __shared__ float sRbf[BM * RBF];
  __shared__ int sXi[BM], sXj[BM];

  const int t  = threadIdx.x;
  const int eb = blockIdx.x * BM;
  const int me = min(BM, E - eb);

  // ---- stage rbf rows + node-type indices ----
  if (t < 96){
    float4 v = make_float4(0.f, 0.f, 0.f, 0.f);
    size_t gi  = (size_t)eb * RBF + (size_t)t * 4;
    size_t lim = (size_t)E * RBF;
    if (gi + 4 <= lim) v = *(const float4*)(rbf + gi);
    else {
      float* pv = (float*)&v;
      for (int c = 0; c < 4; ++c) if (gi + c < lim) pv[c] = rbf[gi + c];
    }
    *(float4*)(sRbf + t*4) = v;
  }
  if (t < BM){
    int xi = 0, xj = 0;
    int e = eb + t;
    if (e < E){ xi = xv[ei[e]]; xj = xv[ej[e]]; }
    sXi[t] = xi; sXj[t] = xj;
  }

  // per-thread fixed k-pair (k = 2t, 2t+1): preload W0 cols + bias
  float2 w0c[RBF];
  #pragma unroll
  for (int r = 0; r < RBF; ++r) w0c[r] = *(const float2*)(W0 + r*HDIM + 2*t);
  float2 bb = *(const float2*)(b0 + 2*t);

  __syncthreads();

  char* sAb = (char*)sA;
  // ---- phase 1: rbf0 tile ----
  {
    const int swz_t = 4 * t;
    #pragma unroll 2
    for (int m = 0; m < BM; ++m){
      float rr[RBF];
      #pragma unroll
      for (int r = 0; r < RBF; ++r) rr[r] = sRbf[m*RBF + r];
      float z0 = bb.x, z1 = bb.y;
      #pragma unroll
      for (int r = 0; r < RBF; ++r){ z0 += rr[r]*w0c[r].x; z1 += rr[r]*w0c[r].y; }
      unsigned pk = (unsigned)f2bf(swishf(z0)) | ((unsigned)f2bf(swishf(z1)) << 16);
      *(unsigned*)(sAb + (m*1024 + (swz_t ^ ((m & 7) << 4)))) = pk;
    }
  }
  __syncthreads();

  // ---- phase 2: MFMA K-loop ----
  const int lane  = t & 63;
  const int w     = t >> 6;
  const int nbase = w * 128;
  const int rlo   = lane & 15;
  const int kg    = lane >> 4;

  f32x4 acc[4][8];
  #pragma unroll
  for (int a = 0; a < 4; ++a)
    #pragma unroll
    for (int b = 0; b < 8; ++b) acc[a][b] = f32x4{0.f, 0.f, 0.f, 0.f};

  for (int ks = 0; ks < 16; ++ks){
    short8 af[4];
    #pragma unroll
    for (int mt = 0; mt < 4; ++mt){
      int row = mt*16 + rlo;
      int off = row*1024 + ((ks*64 + kg*16) ^ ((row & 7) << 4));
      af[mt] = *(const short8*)(sAb + off);
    }
    #pragma unroll
    for (int nt = 0; nt < 8; ++nt){
      int n = nbase + nt*16 + rlo;
      short8 bfr = *(const short8*)(W2T + (size_t)n*HDIM + ks*32 + kg*8);
      #pragma unroll
      for (int mt = 0; mt < 4; ++mt)
        acc[mt][nt] = __builtin_amdgcn_mfma_f32_16x16x32_bf16(af[mt], bfr, acc[mt][nt], 0, 0, 0);
    }
  }

  __syncthreads();   // all waves done reading rbf0 tile

  // ---- phase 3a: g = rbf @ W1 into sA (same swizzle, no bias/swish) ----
  {
    float2 w1c[RBF];
    #pragma unroll
    for (int r = 0; r < RBF; ++r) w1c[r] = *(const float2*)(W1 + r*HDIM + 2*t);
    const int swz_t = 4 * t;
    #pragma unroll 2
    for (int m = 0; m < BM; ++m){
      float rr[RBF];
      #pragma unroll
      for (int r = 0; r < RBF; ++r) rr[r] = sRbf[m*RBF + r];
      float z0 = 0.f, z1 = 0.f;
      #pragma unroll
      for (int r = 0; r < RBF; ++r){ z0 += rr[r]*w1c[r].x; z1 += rr[r]*w1c[r].y; }
      unsigned pk = (unsigned)f2bf(z0) | ((unsigned)f2bf(z1) << 16);
      *(unsigned*)(sAb + (m*1024 + (swz_t ^ ((m & 7) << 4)))) = pk;
    }
  }
  __syncthreads();

  // ---- epilogue ----
  float* __restrict__ out2 = out + (size_t)E * HDIM;
  #pragma unroll
  for (int mt = 0; mt < 4; ++mt){
    #pragma unroll
    for (int r = 0; r < 4; ++r){
      const int m  = mt*16 + kg*4 + r;
      const bool valid = (m < me);
      const int xi = sXi[m], xj = sXj[m];
      const float* p0row = P0 + (size_t)xi * HDIM;
      const float* p1row = P1 + (size_t)xj * HDIM;
      const size_t orow = (size_t)(eb + m) * HDIM;
      #pragma unroll
      for (int nt = 0; nt < 8; ++nt){
        const int n = nbase + nt*16 + rlo;
        float f  = acc[mt][nt][r] + p0row[n] + p1row[n];
        float e1 = swishf(f);
        float g  = bf2f(*(const unsigned short*)(sAb + (m*1024 + ((2*n) ^ ((m & 7) << 4)))));
        if (valid){
          out[orow + n]  = e1;
          out2[orow + n] = g * e1;
        }
      }
    }
  }
}

// ---------------------------------------------------------------------------
extern "C" void kernel_launch(void* const* d_in, const int* in_sizes, int n_in,
                              void* d_out, int out_size, void* d_ws, size_t ws_size,
                              hipStream_t stream) {
  const int*   xv    = (const int*)  d_in[0];
  const float* rbf   = (const float*)d_in[1];
  const int*   ei    = (const int*)  d_in[2];
  const int*   ej    = (const int*)  d_in[3];
  const float* emb   = (const float*)d_in[4];
  const float* W0    = (const float*)d_in[5];
  const float* b0    = (const float*)d_in[6];
  const float* W_lin = (const float*)d_in[7];
  const float* b_lin = (const float*)d_in[8];
  const float* W1    = (const float*)d_in[9];
  float* out = (float*)d_out;

  const int E = in_sizes[2];

  float* P0 = (float*)d_ws;
  float* P1 = P0 + NQ * HDIM;
  unsigned short* W2T = (unsigned short*)(P1 + NQ * HDIM);

  prep_tables<<<2 * NQ, 256, 0, stream>>>(emb, W_lin, b_lin, P0, P1);
  prep_w2t<<<(HDIM * (HDIM/8)) / 256, 256, 0, stream>>>(W_lin, W2T);

  const int nblk = (E + BM - 1) / BM;
  fused_edge<<<nblk, 256, 0, stream>>>(xv, rbf, ei, ej, W0, b0, W1,
                                       P0, P1, W2T, out, E);
}

// Round 2
// 537.412 us; speedup vs baseline: 1.1774x; 1.1774x over previous
//
#include <hip/hip_runtime.h>
#include <hip/hip_bf16.h>

typedef __attribute__((ext_vector_type(8))) short short8;
typedef __attribute__((ext_vector_type(4))) float f32x4;

#define NQ 95
#define HDIM 512
#define RBF 6
#define BM 64

static __device__ __forceinline__ unsigned short f2bf(float f){
  unsigned u = __float_as_uint(f);
  u += 0x7FFF + ((u >> 16) & 1);          // round-to-nearest-even
  return (unsigned short)(u >> 16);
}
static __device__ __forceinline__ float swishf(float z){
  float e = __expf(-z);
  return z * __builtin_amdgcn_rcpf(1.0f + e);
}

// ---------------------------------------------------------------------------
// P0[v][n] = sum_k emb[v][k] * W_lin[k][n]        + b_lin[n]
// P1[v][n] = sum_k emb[v][k] * W_lin[512+k][n]
// ---------------------------------------------------------------------------
__global__ __launch_bounds__(256) void prep_tables(
    const float* __restrict__ emb, const float* __restrict__ W_lin,
    const float* __restrict__ b_lin, float* __restrict__ P0,
    float* __restrict__ P1)
{
  __shared__ float sE[HDIM];
  const int v   = blockIdx.x % NQ;
  const int tab = blockIdx.x / NQ;
  const int t   = threadIdx.x;
  sE[t]       = emb[v*HDIM + t];
  sE[t + 256] = emb[v*HDIM + t + 256];
  __syncthreads();
  const float* W = W_lin + (size_t)tab * HDIM * HDIM;
  float a0 = tab ? 0.f : b_lin[t];
  float a1 = tab ? 0.f : b_lin[t + 256];
  #pragma unroll 4
  for (int k = 0; k < HDIM; ++k){
    float ew = sE[k];
    a0 += ew * W[(size_t)k*HDIM + t];
    a1 += ew * W[(size_t)k*HDIM + t + 256];
  }
  float* P = tab ? P1 : P0;
  P[v*HDIM + t]       = a0;
  P[v*HDIM + t + 256] = a1;
}

// ---------------------------------------------------------------------------
// W2T[n][k] = bf16(W_lin[1024+k][n])   (512x512 bf16, n-major)
// ---------------------------------------------------------------------------
__global__ __launch_bounds__(256) void prep_w2t(
    const float* __restrict__ W_lin, unsigned short* __restrict__ W2T)
{
  const int idx = blockIdx.x * 256 + threadIdx.x;
  const int n  = idx >> 6;
  const int kb = (idx & 63) * 8;
  const float* W2 = W_lin + (size_t)1024 * HDIM;
  unsigned p[4];
  #pragma unroll
  for (int c = 0; c < 4; ++c){
    unsigned lo = f2bf(W2[(size_t)(kb + 2*c    ) * HDIM + n]);
    unsigned hi = f2bf(W2[(size_t)(kb + 2*c + 1) * HDIM + n]);
    p[c] = lo | (hi << 16);
  }
  uint4 o; o.x = p[0]; o.y = p[1]; o.z = p[2]; o.w = p[3];
  *(uint4*)(W2T + (size_t)n * HDIM + kb) = o;
}

// ---------------------------------------------------------------------------
// Fused main kernel, 512 threads (8 waves), 64 edges/block.
//   phase 1: A = bf16(swish(rbf@W0+b0)) [64x512] in LDS (XOR swizzle)
//   phase 2: acc = A @ W2T (each wave: 64 rows x 64 cols)
//   epilogue: e1 = swish(acc + P0[x[i]] + P1[x[j]]); g = rbf@W1 in regs;
//             nontemporal stores (keep W2T L2-resident)
// ---------------------------------------------------------------------------
__global__ __launch_bounds__(512, 4) void fused_edge(
    const int* __restrict__ xv, const float* __restrict__ rbf,
    const int* __restrict__ ei, const int* __restrict__ ej,
    const float* __restrict__ W0, const float* __restrict__ b0,
    const float* __restrict__ W1,
    const float* __restrict__ P0, const float* __restrict__ P1,
    const unsigned short* __restrict__ W2T,
    float* __restrict__ out, int E)
{
  __shared__ unsigned short sA[BM * HDIM];   // 64 KB
  __shared__ float sRbf[BM * RBF];
  __shared__ int sXi[BM], sXj[BM];

  const int t  = threadIdx.x;
  const int eb = blockIdx.x * BM;
  const int me = min(BM, E - eb);

  // ---- stage rbf rows + node-type indices ----
  if (t < 96){
    float4 v = make_float4(0.f, 0.f, 0.f, 0.f);
    size_t gi  = (size_t)eb * RBF + (size_t)t * 4;
    size_t lim = (size_t)E * RBF;
    if (gi + 4 <= lim) v = *(const float4*)(rbf + gi);
    else {
      float* pv = (float*)&v;
      for (int c = 0; c < 4; ++c) if (gi + c < lim) pv[c] = rbf[gi + c];
    }
    *(float4*)(sRbf + t*4) = v;
  } else if (t >= 128 && t < 192){
    int q = t - 128;
    int xi = 0, xj = 0;
    int e = eb + q;
    if (e < E){ xi = xv[ei[e]]; xj = xv[ej[e]]; }
    sXi[q] = xi; sXj[q] = xj;
  }

  // phase-1 assignment: 256 col-pairs x 2 row-halves
  const int cp   = t & 255;        // k-pair: cols 2cp, 2cp+1
  const int half = t >> 8;         // rows half*32 .. half*32+31
  float2 w0c[RBF];
  #pragma unroll
  for (int r = 0; r < RBF; ++r) w0c[r] = *(const float2*)(W0 + r*HDIM + 2*cp);
  float2 bb = *(const float2*)(b0 + 2*cp);

  __syncthreads();

  char* sAb = (char*)sA;
  // ---- phase 1: rbf0 tile ----
  {
    const int swz_t = 4 * cp;
    const int m0 = half * 32;
    #pragma unroll 2
    for (int mm = 0; mm < 32; ++mm){
      const int m = m0 + mm;
      float2 ra = *(const float2*)(sRbf + m*RBF);
      float2 rb = *(const float2*)(sRbf + m*RBF + 2);
      float2 rc = *(const float2*)(sRbf + m*RBF + 4);
      float z0 = bb.x, z1 = bb.y;
      z0 += ra.x*w0c[0].x + ra.y*w0c[1].x + rb.x*w0c[2].x
          + rb.y*w0c[3].x + rc.x*w0c[4].x + rc.y*w0c[5].x;
      z1 += ra.x*w0c[0].y + ra.y*w0c[1].y + rb.x*w0c[2].y
          + rb.y*w0c[3].y + rc.x*w0c[4].y + rc.y*w0c[5].y;
      unsigned pk = (unsigned)f2bf(swishf(z0)) | ((unsigned)f2bf(swishf(z1)) << 16);
      *(unsigned*)(sAb + (m*1024 + (swz_t ^ ((m & 7) << 4)))) = pk;
    }
  }
  __syncthreads();

  // ---- phase 2: MFMA K-loop (wave tile: 64 rows x 64 cols) ----
  const int lane  = t & 63;
  const int w     = t >> 6;
  const int nbase = w * 64;
  const int rlo   = lane & 15;
  const int kg    = lane >> 4;

  f32x4 acc[4][4];
  #pragma unroll
  for (int a = 0; a < 4; ++a)
    #pragma unroll
    for (int b = 0; b < 4; ++b) acc[a][b] = f32x4{0.f, 0.f, 0.f, 0.f};

  for (int ks = 0; ks < 16; ++ks){
    short8 af[4];
    #pragma unroll
    for (int mt = 0; mt < 4; ++mt){
      int row = mt*16 + rlo;
      int off = row*1024 + ((ks*64 + kg*16) ^ ((row & 7) << 4));
      af[mt] = *(const short8*)(sAb + off);
    }
    short8 bfr[4];
    #pragma unroll
    for (int nt = 0; nt < 4; ++nt){
      int n = nbase + nt*16 + rlo;
      bfr[nt] = *(const short8*)(W2T + (size_t)n*HDIM + ks*32 + kg*8);
    }
    #pragma unroll
    for (int nt = 0; nt < 4; ++nt)
      #pragma unroll
      for (int mt = 0; mt < 4; ++mt)
        acc[mt][nt] = __builtin_amdgcn_mfma_f32_16x16x32_bf16(af[mt], bfr[nt], acc[mt][nt], 0, 0, 0);
  }

  // ---- epilogue (no barrier needed: only reads sRbf/sXi/sXj + own acc) ----
  float w1c[RBF][4];
  #pragma unroll
  for (int nt = 0; nt < 4; ++nt){
    int n = nbase + nt*16 + rlo;
    #pragma unroll
    for (int r = 0; r < RBF; ++r) w1c[r][nt] = W1[r*HDIM + n];
  }

  float* __restrict__ out2 = out + (size_t)E * HDIM;
  #pragma unroll
  for (int mt = 0; mt < 4; ++mt){
    #pragma unroll
    for (int r = 0; r < 4; ++r){
      const int m  = mt*16 + kg*4 + r;
      const bool valid = (m < me);
      const int xi = sXi[m], xj = sXj[m];
      const float* p0row = P0 + (size_t)xi * HDIM;
      const float* p1row = P1 + (size_t)xj * HDIM;
      const size_t orow = (size_t)(eb + m) * HDIM;
      float2 rra = *(const float2*)(sRbf + m*RBF);
      float2 rrb = *(const float2*)(sRbf + m*RBF + 2);
      float2 rrc = *(const float2*)(sRbf + m*RBF + 4);
      #pragma unroll
      for (int nt = 0; nt < 4; ++nt){
        const int n = nbase + nt*16 + rlo;
        float f  = acc[mt][nt][r] + p0row[n] + p1row[n];
        float e1 = swishf(f);
        float g  = rra.x*w1c[0][nt] + rra.y*w1c[1][nt] + rrb.x*w1c[2][nt]
                 + rrb.y*w1c[3][nt] + rrc.x*w1c[4][nt] + rrc.y*w1c[5][nt];
        if (valid){
          __builtin_nontemporal_store(e1,    out  + orow + n);
          __builtin_nontemporal_store(g*e1,  out2 + orow + n);
        }
      }
    }
  }
}

// ---------------------------------------------------------------------------
extern "C" void kernel_launch(void* const* d_in, const int* in_sizes, int n_in,
                              void* d_out, int out_size, void* d_ws, size_t ws_size,
                              hipStream_t stream) {
  const int*   xv    = (const int*)  d_in[0];
  const float* rbf   = (const float*)d_in[1];
  const int*   ei    = (const int*)  d_in[2];
  const int*   ej    = (const int*)  d_in[3];
  const float* emb   = (const float*)d_in[4];
  const float* W0    = (const float*)d_in[5];
  const float* b0    = (const float*)d_in[6];
  const float* W_lin = (const float*)d_in[7];
  const float* b_lin = (const float*)d_in[8];
  const float* W1    = (const float*)d_in[9];
  float* out = (float*)d_out;

  const int E = in_sizes[2];

  float* P0 = (float*)d_ws;
  float* P1 = P0 + NQ * HDIM;
  unsigned short* W2T = (unsigned short*)(P1 + NQ * HDIM);

  prep_tables<<<2 * NQ, 256, 0, stream>>>(emb, W_lin, b_lin, P0, P1);
  prep_w2t<<<(HDIM * (HDIM/8)) / 256, 256, 0, stream>>>(W_lin, W2T);

  const int nblk = (E + BM - 1) / BM;
  fused_edge<<<nblk, 512, 0, stream>>>(xv, rbf, ei, ej, W0, b0, W1,
                                       P0, P1, W2T, out, E);
}